// Round 10
// baseline (494.736 us; speedup 1.0000x reference)
//
#include <hip/hip_runtime.h>
#include <hip/hip_bf16.h>

#define B_ 4
#define T_ 128
#define U_ 64
#define D_ 512
#define H_ 640
#define V_ 1024

typedef float f32x4 __attribute__((ext_vector_type(4)));
typedef __bf16 bf16x8 __attribute__((ext_vector_type(8)));

union U4BF8 { uint4 u; bf16x8 v; };

__device__ __forceinline__ unsigned short f2bf(float x) {
  union { float f; unsigned int u; } a; a.f = x;
  unsigned int r = a.u + 0x7FFFu + ((a.u >> 16) & 1u);
  return (unsigned short)(r >> 16);
}

// ---------------------------------------------------------------------------
// P0 fused prep (one launch, R4-proven):
//  blocks 0..191  : proj  ps = SRC@W1[:D] (512x640); pt = TGT@W1[D:]+b1
//  blocks 192..271: pack  W2 -> bf16 fragment cells with column permute
//    (packed p = wid*64+nf*16+l16 holds original col wid*64+l16*4+nf).
// ---------------------------------------------------------------------------
__global__ __launch_bounds__(640) void k_prep(
    const float* __restrict__ W2, uint4* __restrict__ w2p,
    const int* __restrict__ slen, const int* __restrict__ tlen,
    float* __restrict__ out_tail,
    const float* __restrict__ src, const float* __restrict__ tgt,
    const float* __restrict__ W1, const float* __restrict__ b1,
    float* __restrict__ ps, float* __restrict__ pt) {
  __shared__ __align__(16) float lin[D_ * 4];
  int bid = blockIdx.x, tid = threadIdx.x;
  if (bid < 192) {
    bool is_t = bid >= 128;
    const float* in; const float* w; float* outp;
    if (!is_t) {
      int r0 = bid * 4;
      in = src + (size_t)r0 * D_; w = W1; outp = ps + (size_t)r0 * H_;
    } else {
      int r0 = (bid - 128) * 4;
      in = tgt + (size_t)r0 * D_; w = W1 + (size_t)D_ * H_; outp = pt + (size_t)r0 * H_;
    }
    for (int idx = tid; idx < 4 * D_; idx += 640) {
      int r = idx >> 9, k = idx & (D_ - 1);
      lin[k * 4 + r] = in[idx];
    }
    __syncthreads();
    float a0 = 0.f, a1 = 0.f, a2 = 0.f, a3 = 0.f;
    int j = tid;
    for (int k = 0; k < D_; ++k) {
      float wv = w[(size_t)k * H_ + j];
      f32x4 x = *(const f32x4*)&lin[k * 4];
      a0 += x[0] * wv; a1 += x[1] * wv; a2 += x[2] * wv; a3 += x[3] * wv;
    }
    float bb = is_t ? b1[j] : 0.f;
    outp[0 * H_ + j] = a0 + bb;
    outp[1 * H_ + j] = a1 + bb;
    outp[2 * H_ + j] = a2 + bb;
    outp[3 * H_ + j] = a3 + bb;
  } else {
    int kq = bid - 192;            // 0..79
    for (int n = tid; n < V_; n += 640) {
      int src_n = (n & ~63) | ((n & 15) * 4) | ((n >> 4) & 3);
      float f[8];
      #pragma unroll
      for (int j = 0; j < 8; ++j) f[j] = W2[(size_t)(kq * 8 + j) * V_ + src_n];
      unsigned int w[4];
      #pragma unroll
      for (int j = 0; j < 4; ++j)
        w[j] = (unsigned)f2bf(f[2 * j]) | ((unsigned)f2bf(f[2 * j + 1]) << 16);
      uint4 p; p.x = w[0]; p.y = w[1]; p.z = w[2]; p.w = w[3];
      w2p[(size_t)kq * V_ + n] = p;
    }
    if (bid == 192 && tid < 8)
      out_tail[tid] = (tid < 4) ? (float)slen[tid] : (float)tlen[tid - 4];
  }
}

// ---------------------------------------------------------------------------
// Main: 256 blocks (= 1/CU) x 1024 threads. M=128 (TWO t's) x N=1024 per
// block. Rationale: R3/R7/R9 all hit 88us because each block streams the
// full 1.31MB W2p from L2 with zero L1 reuse; achieved per-CU pure-L2 rate
// ~37GB/s is the cap (2 blocks/CU x 1.31MB / 37GB/s ~= 71us ~= observed).
// Doubling M halves unique L2 bytes per output row: each CU now streams W2p
// ONCE. acc[8][4]=128 f32/thread at __launch_bounds__(1024,2): 256-reg
// budget, ~210 used, no spill (bb dies in-iter; FETCH_SIZE is the canary).
// A panel (128x640 bf16) K-chunked x2 into 84KB LDS (affine [m][kq] rows,
// stride 41 cells). Softmax block-local (full V row). 32 MFMA / 12 loads.
// ---------------------------------------------------------------------------
__global__ __launch_bounds__(1024, 2) void k_joint(
    const float* __restrict__ ps, const float* __restrict__ pt,
    const uint4* __restrict__ w2p, const float* __restrict__ b2,
    float* __restrict__ out) {
  __shared__ uint4 ldsA[128 * 41];         // 84KB, [m][kq] padded rows
  __shared__ float red[16][128][2];        // 16KB
  __shared__ float lzs[128];
  int bid = blockIdx.x;                    // 0..255
  int xcd = bid & 7;
  int b = xcd >> 1;                        // one batch per XCD pair
  int t0 = ((bid >> 3) + (xcd & 1) * 32) * 2;   // 0,2,..,126
  int tid = threadIdx.x;
  int lane = tid & 63, wid = tid >> 6;     // wid 0..15
  int l16 = lane & 15, lg = lane >> 4;

  int gm = tid >> 3;                       // gen row 0..127
  int gq = (tid & 7) * 5;                  // gen kq base (5 cells/thread)
  const float* gps = ps + (size_t)(b * T_ + t0 + (gm >> 6)) * H_;
  const float* gpt = pt + (size_t)(b * U_ + (gm & 63)) * H_;
  uint4* grow = &ldsA[gm * 41 + gq];

  f32x4 acc[8][4];
  #pragma unroll
  for (int mf = 0; mf < 8; ++mf)
    #pragma unroll
    for (int nf = 0; nf < 4; ++nf) {
      f32x4 z = {0.f, 0.f, 0.f, 0.f};
      acc[mf][nf] = z;
    }

  for (int ch = 0; ch < 2; ++ch) {
    if (ch) __syncthreads();               // protect ldsA overwrite
    // ---- gen: A[m][kq] = tanh(ps+pt) bf16, 5 cells/thread ----
    #pragma unroll
    for (int i = 0; i < 5; ++i) {
      int kg = ch * 40 + gq + i;
      const float4* pp = (const float4*)(gps + kg * 8);
      const float4* qq = (const float4*)(gpt + kg * 8);
      float4 p0 = pp[0], p1 = pp[1];
      float4 q0 = qq[0], q1 = qq[1];
      float x[8] = {p0.x + q0.x, p0.y + q0.y, p0.z + q0.z, p0.w + q0.w,
                    p1.x + q1.x, p1.y + q1.y, p1.z + q1.z, p1.w + q1.w};
      unsigned int wv[4];
      #pragma unroll
      for (int j = 0; j < 4; ++j) {
        float e0 = __expf(2.f * x[2 * j]);
        float h0 = 1.f - 2.f * __builtin_amdgcn_rcpf(e0 + 1.f);
        float e1 = __expf(2.f * x[2 * j + 1]);
        float h1 = 1.f - 2.f * __builtin_amdgcn_rcpf(e1 + 1.f);
        wv[j] = (unsigned)f2bf(h0) | ((unsigned)f2bf(h1) << 16);
      }
      uint4 pk; pk.x = wv[0]; pk.y = wv[1]; pk.z = wv[2]; pk.w = wv[3];
      grow[i] = pk;
    }
    __syncthreads();

    // ---- MFMA: 10 kq-steps of K=32; B streamed from L2, A from LDS ----
    const uint4* arow = ldsA + l16 * 41 + lg;
    const uint4* bp = w2p + (size_t)(ch * 40 + lg) * 1024 + wid * 64 + l16;
    for (int kq0 = 0; kq0 < 40; kq0 += 4) {
      U4BF8 a[8];
      #pragma unroll
      for (int mf = 0; mf < 8; ++mf)
        a[mf].u = arow[mf * (16 * 41) + kq0];
      U4BF8 bb[4];
      const uint4* bpi = bp + (size_t)kq0 * 1024;
      #pragma unroll
      for (int nf = 0; nf < 4; ++nf) bb[nf].u = bpi[nf * 16];
      #pragma unroll
      for (int nf = 0; nf < 4; ++nf)
        #pragma unroll
        for (int mf = 0; mf < 8; ++mf)
          acc[mf][nf] = __builtin_amdgcn_mfma_f32_16x16x32_bf16(
              a[mf].v, bb[nf].v, acc[mf][nf], 0, 0, 0);
    }
  }

  // ---- epilogue: fold b2 (permuted cols), log_softmax, nt f32x4 store ----
  {
    f32x4 b2v = *(const f32x4*)&b2[wid * 64 + l16 * 4];
    #pragma unroll
    for (int mf = 0; mf < 8; ++mf)
      #pragma unroll
      for (int nf = 0; nf < 4; ++nf)
        #pragma unroll
        for (int r = 0; r < 4; ++r)
          acc[mf][nf][r] += b2v[nf];
  }

  #pragma unroll
  for (int mf = 0; mf < 8; ++mf)
    #pragma unroll
    for (int r = 0; r < 4; ++r) {
      float pm = -3.4e38f;
      #pragma unroll
      for (int nf = 0; nf < 4; ++nf) pm = fmaxf(pm, acc[mf][nf][r]);
      pm = fmaxf(pm, __shfl_xor(pm, 1));
      pm = fmaxf(pm, __shfl_xor(pm, 2));
      pm = fmaxf(pm, __shfl_xor(pm, 4));
      pm = fmaxf(pm, __shfl_xor(pm, 8));
      float s = 0.f;
      #pragma unroll
      for (int nf = 0; nf < 4; ++nf) s += __expf(acc[mf][nf][r] - pm);
      s += __shfl_xor(s, 1);
      s += __shfl_xor(s, 2);
      s += __shfl_xor(s, 4);
      s += __shfl_xor(s, 8);
      if (l16 == 0) {
        int row = mf * 16 + lg * 4 + r;
        red[wid][row][0] = pm;
        red[wid][row][1] = s;
      }
    }
  __syncthreads();

  if (tid < 128) {
    float M = -3.4e38f;
    #pragma unroll
    for (int w16 = 0; w16 < 16; ++w16) M = fmaxf(M, red[w16][tid][0]);
    float S = 0.f;
    #pragma unroll
    for (int w16 = 0; w16 < 16; ++w16)
      S += red[w16][tid][1] * __expf(red[w16][tid][0] - M);
    lzs[tid] = M + __logf(S);
  }
  __syncthreads();

  float* outb = out + (size_t)(b * T_ + t0) * U_ * V_;
  #pragma unroll
  for (int mf = 0; mf < 8; ++mf)
    #pragma unroll
    for (int r = 0; r < 4; ++r) {
      int row = mf * 16 + lg * 4 + r;   // 0..127 = t_loc*64 + u
      float lz = lzs[row];
      f32x4 o;
      o[0] = acc[mf][0][r] - lz;
      o[1] = acc[mf][1][r] - lz;
      o[2] = acc[mf][2][r] - lz;
      o[3] = acc[mf][3][r] - lz;
      __builtin_nontemporal_store(
          o, (f32x4*)&outb[(size_t)row * V_ + wid * 64 + l16 * 4]);
    }
}

extern "C" void kernel_launch(void* const* d_in, const int* in_sizes, int n_in,
                              void* d_out, int out_size, void* d_ws, size_t ws_size,
                              hipStream_t stream) {
  const float* src = (const float*)d_in[0];
  const int*   slen = (const int*)d_in[1];
  const float* tgt = (const float*)d_in[2];
  const int*   tlen = (const int*)d_in[3];
  const float* W1 = (const float*)d_in[4];
  const float* b1 = (const float*)d_in[5];
  const float* W2 = (const float*)d_in[6];
  const float* b2 = (const float*)d_in[7];
  float* out = (float*)d_out;

  float* ps  = (float*)d_ws;                 // 512*640 f32
  float* pt  = ps + 512 * 640;               // 256*640 f32
  uint4* w2p = (uint4*)(pt + 256 * 640);     // 80*1024 uint4 (bf16 packed W2)

  k_prep<<<272, 640, 0, stream>>>(W2, w2p, slen, tlen,
                                  out + (size_t)B_ * T_ * U_ * V_,
                                  src, tgt, W1, b1, ps, pt);
  k_joint<<<256, 1024, 0, stream>>>(ps, pt, w2p, b2, out);
}

// Round 11
// 98.109 us; speedup vs baseline: 5.0427x; 5.0427x over previous
//
#include <hip/hip_runtime.h>
#include <hip/hip_bf16.h>

#define B_ 4
#define T_ 128
#define U_ 64
#define D_ 512
#define H_ 640
#define V_ 1024

typedef float f32x4 __attribute__((ext_vector_type(4)));

union U2L { uint2 u; long long l; };
union U4L2 { uint4 u; long long l[2]; };

// ---------------------------------------------------------------------------
// P0 fused prep (one launch):
//  blocks 0..191  : proj  ps = SRC@W1[:D] (512x640); pt = TGT@W1[D:]+b1
//  blocks 192..271: pack  W2 -> fp8 e4m3 fragment cells, column-permuted
//    (frag (kq,wid,nf,l16) holds original col wid*64 + l16*4 + nf so the 4
//    nf-accumulators are 4 consecutive output cols -> f32x4 stores).
//    Physical layout: uint2 cell at [kq*1024 + wid*64 + (nf>>1)*32 + l16*2
//    + (nf&1)] so one uint4 load covers the nf pair {2h, 2h+1}.
// ---------------------------------------------------------------------------
__global__ __launch_bounds__(640) void k_prep(
    const float* __restrict__ W2, uint2* __restrict__ w2p8,
    const int* __restrict__ slen, const int* __restrict__ tlen,
    float* __restrict__ out_tail,
    const float* __restrict__ src, const float* __restrict__ tgt,
    const float* __restrict__ W1, const float* __restrict__ b1,
    float* __restrict__ ps, float* __restrict__ pt) {
  __shared__ __align__(16) float lin[D_ * 4];
  int bid = blockIdx.x, tid = threadIdx.x;
  if (bid < 192) {
    bool is_t = bid >= 128;
    const float* in; const float* w; float* outp;
    if (!is_t) {
      int r0 = bid * 4;
      in = src + (size_t)r0 * D_; w = W1; outp = ps + (size_t)r0 * H_;
    } else {
      int r0 = (bid - 128) * 4;
      in = tgt + (size_t)r0 * D_; w = W1 + (size_t)D_ * H_; outp = pt + (size_t)r0 * H_;
    }
    for (int idx = tid; idx < 4 * D_; idx += 640) {
      int r = idx >> 9, k = idx & (D_ - 1);
      lin[k * 4 + r] = in[idx];
    }
    __syncthreads();
    float a0 = 0.f, a1 = 0.f, a2 = 0.f, a3 = 0.f;
    int j = tid;
    for (int k = 0; k < D_; ++k) {
      float wv = w[(size_t)k * H_ + j];
      f32x4 x = *(const f32x4*)&lin[k * 4];
      a0 += x[0] * wv; a1 += x[1] * wv; a2 += x[2] * wv; a3 += x[3] * wv;
    }
    float bb = is_t ? b1[j] : 0.f;
    outp[0 * H_ + j] = a0 + bb;
    outp[1 * H_ + j] = a1 + bb;
    outp[2 * H_ + j] = a2 + bb;
    outp[3 * H_ + j] = a3 + bb;
  } else {
    int kq = bid - 192;            // 0..79
    for (int idx = tid; idx < V_; idx += 640) {
      int wid = idx >> 6, rem = idx & 63, nf = rem >> 4, l16 = rem & 15;
      int col = wid * 64 + l16 * 4 + nf;
      float f[8];
      #pragma unroll
      for (int j = 0; j < 8; ++j) f[j] = W2[(size_t)(kq * 8 + j) * V_ + col];
      int d0 = __builtin_amdgcn_cvt_pk_fp8_f32(f[0], f[1], 0, 0);
      d0 = __builtin_amdgcn_cvt_pk_fp8_f32(f[2], f[3], d0, 1);
      int d1 = __builtin_amdgcn_cvt_pk_fp8_f32(f[4], f[5], 0, 0);
      d1 = __builtin_amdgcn_cvt_pk_fp8_f32(f[6], f[7], d1, 1);
      uint2 c; c.x = (unsigned)d0; c.y = (unsigned)d1;
      w2p8[(size_t)kq * 1024 + wid * 64 + (nf >> 1) * 32 + l16 * 2 + (nf & 1)] = c;
    }
    if (bid == 192 && tid < 8)
      out_tail[tid] = (tid < 4) ? (float)slen[tid] : (float)tlen[tid - 4];
  }
}

// ---------------------------------------------------------------------------
// Main: 512 blocks x 1024 threads, R7 structure, fp8 operands.
// Register wall (R10 lesson): VGPR pool = 512/SIMD; a 16-wave block caps at
// 128 regs/thread -> acc[4][4]=64 + fp8 frags (a:8, bb:8) + addr ~= 100 OK.
// fp8 halves the per-block B stream (1.31MB -> 672KB) and A-LDS (80->41KB):
// if the 88us wall is B-byte streaming (L2 port / L1 fill / miss queue),
// the K-loop phase ~halves. MFMA count/rate unchanged (16x16x32 fp8 = bf16
// rate). A cell(m,kq) = 8 fp8 (k=8kq..8kq+7) at ldsA[m*81+kq] (affine,
// conflict-free quarter-wave on both write and read).
// ---------------------------------------------------------------------------
__global__ __launch_bounds__(1024, 4) void k_joint(
    const float* __restrict__ ps, const float* __restrict__ pt,
    const uint2* __restrict__ w2p8, const float* __restrict__ b2,
    float* __restrict__ out) {
  __shared__ uint2 ldsA[64 * 81];          // 41.5 KiB, [m][kq] padded rows
  __shared__ float red[16][64][2];         // 8 KiB
  __shared__ float lzs[64];
  int bid = blockIdx.x;                    // 0..511
  int xcd = bid & 7;
  int b = xcd >> 1;                        // one batch per XCD pair
  int t = (bid >> 3) + (xcd & 1) * 64;     // 0..127
  int tid = threadIdx.x;
  int lane = tid & 63, wid = tid >> 6;     // wid 0..15
  int l16 = lane & 15, lg = lane >> 4;
  const float* psrow = ps + (size_t)(b * T_ + t) * H_;

  // ---- phase 1: A generation -> fp8, thread owns row gm, cols i*16+gk ----
  {
    int gm = tid >> 4;                     // 0..63
    int gk = tid & 15;
    const float* ptrow = pt + (size_t)(b * U_ + gm) * H_;
    uint2* wrow = &ldsA[gm * 81];
    #pragma unroll
    for (int i = 0; i < 5; ++i) {
      int kq = i * 16 + gk;
      const float4* pp = (const float4*)(psrow + kq * 8);
      const float4* qq = (const float4*)(ptrow + kq * 8);
      float4 p0 = pp[0], p1 = pp[1];
      float4 q0 = qq[0], q1 = qq[1];
      float x[8] = {p0.x + q0.x, p0.y + q0.y, p0.z + q0.z, p0.w + q0.w,
                    p1.x + q1.x, p1.y + q1.y, p1.z + q1.z, p1.w + q1.w};
      float h[8];
      #pragma unroll
      for (int j = 0; j < 8; ++j) {
        float e = __expf(2.f * x[j]);
        h[j] = 1.f - 2.f * __builtin_amdgcn_rcpf(e + 1.f);
      }
      int d0 = __builtin_amdgcn_cvt_pk_fp8_f32(h[0], h[1], 0, 0);
      d0 = __builtin_amdgcn_cvt_pk_fp8_f32(h[2], h[3], d0, 1);
      int d1 = __builtin_amdgcn_cvt_pk_fp8_f32(h[4], h[5], 0, 0);
      d1 = __builtin_amdgcn_cvt_pk_fp8_f32(h[6], h[7], d1, 1);
      uint2 c; c.x = (unsigned)d0; c.y = (unsigned)d1;
      wrow[kq] = c;
    }
  }
  __syncthreads();

  f32x4 acc[4][4];
  #pragma unroll
  for (int mf = 0; mf < 4; ++mf)
    #pragma unroll
    for (int nf = 0; nf < 4; ++nf) {
      f32x4 z = {0.f, 0.f, 0.f, 0.f};
      acc[mf][nf] = z;
    }

  // ---- phase 2: K loop (20 iters of K=32), fp8 MFMA, affine addresses ----
  {
    const uint2* arow = ldsA + l16 * 81 + lg;        // + kq0 per iter
    const uint4* bp = (const uint4*)w2p8 + (size_t)lg * 512 + wid * 32 + l16;
    for (int kq0 = 0; kq0 < 80; kq0 += 4) {
      U2L a[4];
      #pragma unroll
      for (int mf = 0; mf < 4; ++mf)
        a[mf].u = arow[mf * (16 * 81) + kq0];        // b64 reads
      U4L2 q0, q1;
      const uint4* bpi = bp + (size_t)kq0 * 512;
      q0.u = bpi[0];                                 // nf 0,1
      q1.u = bpi[16];                                // nf 2,3
      long long bbl[4] = {q0.l[0], q0.l[1], q1.l[0], q1.l[1]};
      #pragma unroll
      for (int nf = 0; nf < 4; ++nf)
        #pragma unroll
        for (int mf = 0; mf < 4; ++mf)
          acc[mf][nf] = __builtin_amdgcn_mfma_f32_16x16x32_fp8_fp8(
              a[mf].l, bbl[nf], acc[mf][nf], 0, 0, 0);
    }
  }

  // ---- phase 3: fold b2 (permuted cols), log_softmax, nt f32x4 store ----
  {
    f32x4 b2v = *(const f32x4*)&b2[wid * 64 + l16 * 4];
    #pragma unroll
    for (int mf = 0; mf < 4; ++mf)
      #pragma unroll
      for (int nf = 0; nf < 4; ++nf)
        #pragma unroll
        for (int r = 0; r < 4; ++r)
          acc[mf][nf][r] += b2v[nf];
  }

  #pragma unroll
  for (int mf = 0; mf < 4; ++mf)
    #pragma unroll
    for (int r = 0; r < 4; ++r) {
      float pm = -3.4e38f;
      #pragma unroll
      for (int nf = 0; nf < 4; ++nf) pm = fmaxf(pm, acc[mf][nf][r]);
      pm = fmaxf(pm, __shfl_xor(pm, 1));
      pm = fmaxf(pm, __shfl_xor(pm, 2));
      pm = fmaxf(pm, __shfl_xor(pm, 4));
      pm = fmaxf(pm, __shfl_xor(pm, 8));
      float s = 0.f;
      #pragma unroll
      for (int nf = 0; nf < 4; ++nf) s += __expf(acc[mf][nf][r] - pm);
      s += __shfl_xor(s, 1);
      s += __shfl_xor(s, 2);
      s += __shfl_xor(s, 4);
      s += __shfl_xor(s, 8);
      if (l16 == 0) {
        int row = mf * 16 + lg * 4 + r;
        red[wid][row][0] = pm;
        red[wid][row][1] = s;
      }
    }
  __syncthreads();

  if (tid < 64) {
    float M = -3.4e38f;
    #pragma unroll
    for (int w16 = 0; w16 < 16; ++w16) M = fmaxf(M, red[w16][tid][0]);
    float S = 0.f;
    #pragma unroll
    for (int w16 = 0; w16 < 16; ++w16)
      S += red[w16][tid][1] * __expf(red[w16][tid][0] - M);
    lzs[tid] = M + __logf(S);
  }
  __syncthreads();

  float* outb = out + (size_t)(b * T_ + t) * U_ * V_;
  #pragma unroll
  for (int mf = 0; mf < 4; ++mf)
    #pragma unroll
    for (int r = 0; r < 4; ++r) {
      int row = mf * 16 + lg * 4 + r;
      float lz = lzs[row];
      f32x4 o;
      o[0] = acc[mf][0][r] - lz;
      o[1] = acc[mf][1][r] - lz;
      o[2] = acc[mf][2][r] - lz;
      o[3] = acc[mf][3][r] - lz;
      __builtin_nontemporal_store(
          o, (f32x4*)&outb[(size_t)row * V_ + wid * 64 + l16 * 4]);
    }
}

extern "C" void kernel_launch(void* const* d_in, const int* in_sizes, int n_in,
                              void* d_out, int out_size, void* d_ws, size_t ws_size,
                              hipStream_t stream) {
  const float* src = (const float*)d_in[0];
  const int*   slen = (const int*)d_in[1];
  const float* tgt = (const float*)d_in[2];
  const int*   tlen = (const int*)d_in[3];
  const float* W1 = (const float*)d_in[4];
  const float* b1 = (const float*)d_in[5];
  const float* W2 = (const float*)d_in[6];
  const float* b2 = (const float*)d_in[7];
  float* out = (float*)d_out;

  float* ps   = (float*)d_ws;                 // 512*640 f32
  float* pt   = ps + 512 * 640;               // 256*640 f32
  uint2* w2p8 = (uint2*)(pt + 256 * 640);     // 80*1024 uint2 (fp8 packed W2)

  k_prep<<<272, 640, 0, stream>>>(W2, w2p8, slen, tlen,
                                  out + (size_t)B_ * T_ * U_ * V_,
                                  src, tgt, W1, b1, ps, pt);
  k_joint<<<512, 1024, 0, stream>>>(ps, pt, w2p8, b2, out);
}